// Round 1
// baseline (477.706 us; speedup 1.0000x reference)
//
#include <hip/hip_runtime.h>

typedef _Float16 half8 __attribute__((ext_vector_type(8)));
typedef _Float16 half4 __attribute__((ext_vector_type(4)));
typedef float floatx4 __attribute__((ext_vector_type(4)));

#define NB 8        // batches per block
#define SX 136      // Xs/Qs/Ks row stride (fp16): 128 + 8 pad -> optimal b128 bank spread
#define SVT 72      // Vt row stride: 64 + 8 pad
#define SP 80       // Ps row stride: 64 + 16 pad

// Convert [Wq|Wk|Wv|Wr] (each 128x128 fp32) into Wc[128][512] fp16 in workspace.
__global__ void wconv_kernel(const float* __restrict__ Wq, const float* __restrict__ Wk,
                             const float* __restrict__ Wv, const float* __restrict__ Wr,
                             _Float16* __restrict__ Wh) {
    int idx = blockIdx.x * 256 + threadIdx.x;   // 0 .. 65535
    int row = idx >> 9;
    int col = idx & 511;
    const float* s = (col < 128) ? Wq : (col < 256) ? Wk : (col < 384) ? Wv : Wr;
    Wh[idx] = (_Float16)s[row * 128 + (col & 127)];
}

__global__ __launch_bounds__(512, 2)
void autoint_kernel(const float* __restrict__ xg, const _Float16* __restrict__ Wh,
                    float* __restrict__ outg) {
    const int tid  = threadIdx.x;
    const int w    = tid >> 6;        // wave id 0..7
    const int lane = tid & 63;
    const int nn   = lane & 15;       // MFMA n / col-in-tile
    const int q    = lane >> 4;       // MFMA quad
    const long b0  = (long)blockIdx.x * NB;

    // 62 KB static LDS
    __shared__ _Float16 lds[31744];
    _Float16* Xs = lds;               // 64 x 136 = 8704   (shares buffer with Vt)
    _Float16* Vt = lds;               // 128 x 72 = 9216   (V transposed: [feature][key])
    _Float16* Qs = lds + 9216;        // 64 x 136
    _Float16* Ks = lds + 17920;       // 64 x 136
    _Float16* Ps = lds + 26624;       // 64 x 80  = 5120

    // ---- hoist weight B-fragments into registers (reused across NB batches) ----
    // col-tile map: waves 0-1 -> Q (ct 0-7), waves 2-3 -> K (ct 8-15),
    // waves 4-7: local c<2 -> V (ct 16-23), c>=2 -> R (ct 24-31)
    half8 wf[4][4];
    #pragma unroll
    for (int c = 0; c < 4; ++c) {
        int ctg;
        if (w < 4) ctg = 4 * w + c;
        else       ctg = (c < 2) ? (16 + 2 * (w - 4) + c) : (24 + 2 * (w - 4) + (c - 2));
        int col = ctg * 16 + nn;
        #pragma unroll
        for (int ks = 0; ks < 4; ++ks) {
            half8 f;
            #pragma unroll
            for (int i = 0; i < 8; ++i)
                f[i] = Wh[(ks * 32 + q * 8 + i) * 512 + col];
            wf[c][ks] = f;
        }
    }

    // ---- prologue: stage X(b0) into LDS (waves 0-3) ----
    float4 pf[8];
    if (w < 4) {
        const float4* Xg = (const float4*)(xg + b0 * 8192);
        #pragma unroll
        for (int t = 0; t < 8; ++t) pf[t] = Xg[t * 256 + tid];
        #pragma unroll
        for (int t = 0; t < 8; ++t) {
            int g = t * 256 + tid;
            int row = g >> 5, c4 = (g & 31) * 4;
            half4 h = { (_Float16)pf[t].x, (_Float16)pf[t].y,
                        (_Float16)pf[t].z, (_Float16)pf[t].w };
            *(half4*)(Xs + row * SX + c4) = h;
        }
    }
    __syncthreads();

    for (int it = 0; it < NB; ++it) {
        const long b = b0 + it;

        // prefetch next batch's X into registers (hides HBM latency across the iteration)
        if (w < 4 && it + 1 < NB) {
            const float4* Xg = (const float4*)(xg + (b + 1) * 8192);
            #pragma unroll
            for (int t = 0; t < 8; ++t) pf[t] = Xg[t * 256 + tid];
        }

        // ---- phase 2: projections  C(64x512) = X(64x128) @ Wc(128x512) ----
        floatx4 acc[4][4];
        {
            floatx4 z = {0.f, 0.f, 0.f, 0.f};
            #pragma unroll
            for (int rt = 0; rt < 4; ++rt)
                #pragma unroll
                for (int c = 0; c < 4; ++c) acc[rt][c] = z;
        }
        #pragma unroll
        for (int ks = 0; ks < 4; ++ks) {
            half8 a[4];
            #pragma unroll
            for (int rt = 0; rt < 4; ++rt)
                a[rt] = *(const half8*)(Xs + (rt * 16 + nn) * SX + ks * 32 + q * 8);
            #pragma unroll
            for (int rt = 0; rt < 4; ++rt)
                #pragma unroll
                for (int c = 0; c < 4; ++c)
                    acc[rt][c] = __builtin_amdgcn_mfma_f32_16x16x32_f16(
                        a[rt], wf[c][ks], acc[rt][c], 0, 0, 0);
        }
        __syncthreads();   // Xs consumed -> buffer free for Vt

        // ---- phase 3: scatter Q, K, V^T to LDS (R stays in regs of waves 4-7) ----
        if (w < 2) {
            #pragma unroll
            for (int rt = 0; rt < 4; ++rt)
                #pragma unroll
                for (int c = 0; c < 4; ++c) {
                    int f = (4 * w + c) * 16 + nn;
                    #pragma unroll
                    for (int r = 0; r < 4; ++r)
                        Qs[(rt * 16 + q * 4 + r) * SX + f] = (_Float16)acc[rt][c][r];
                }
        } else if (w < 4) {
            #pragma unroll
            for (int rt = 0; rt < 4; ++rt)
                #pragma unroll
                for (int c = 0; c < 4; ++c) {
                    int f = (4 * w + c - 8) * 16 + nn;
                    #pragma unroll
                    for (int r = 0; r < 4; ++r)
                        Ks[(rt * 16 + q * 4 + r) * SX + f] = (_Float16)acc[rt][c][r];
                }
        } else {
            int j = w - 4;
            #pragma unroll
            for (int rt = 0; rt < 4; ++rt)
                #pragma unroll
                for (int c = 0; c < 2; ++c) {
                    int f = (2 * j + c) * 16 + nn;   // feature col 0..127
                    half4 hv = { (_Float16)acc[rt][c][0], (_Float16)acc[rt][c][1],
                                 (_Float16)acc[rt][c][2], (_Float16)acc[rt][c][3] };
                    *(half4*)(Vt + f * SVT + rt * 16 + q * 4) = hv;  // keys contiguous
                }
        }
        __syncthreads();   // Q, K, Vt visible

        // ---- phase 4+5: scores S = Q K^T, softmax, P (waves 0-3; wave w owns rows w*16..+15) ----
        if (w < 4) {
            floatx4 sacc[4];
            {
                floatx4 z = {0.f, 0.f, 0.f, 0.f};
                #pragma unroll
                for (int c = 0; c < 4; ++c) sacc[c] = z;
            }
            #pragma unroll
            for (int ks = 0; ks < 4; ++ks) {
                half8 aq = *(const half8*)(Qs + (w * 16 + nn) * SX + ks * 32 + q * 8);
                #pragma unroll
                for (int c = 0; c < 4; ++c) {
                    half8 bk = *(const half8*)(Ks + (c * 16 + nn) * SX + ks * 32 + q * 8);
                    sacc[c] = __builtin_amdgcn_mfma_f32_16x16x32_f16(aq, bk, sacc[c], 0, 0, 0);
                }
            }
            // softmax: row (w*16 + q*4 + r) lives in the 16 lanes of quad q (4 ct regs each)
            #pragma unroll
            for (int r = 0; r < 4; ++r) {
                float mx = fmaxf(fmaxf(sacc[0][r], sacc[1][r]), fmaxf(sacc[2][r], sacc[3][r]));
                mx = fmaxf(mx, __shfl_xor(mx, 1));
                mx = fmaxf(mx, __shfl_xor(mx, 2));
                mx = fmaxf(mx, __shfl_xor(mx, 4));
                mx = fmaxf(mx, __shfl_xor(mx, 8));
                float e0 = __expf(sacc[0][r] - mx);
                float e1 = __expf(sacc[1][r] - mx);
                float e2 = __expf(sacc[2][r] - mx);
                float e3 = __expf(sacc[3][r] - mx);
                float s = e0 + e1 + e2 + e3;
                s += __shfl_xor(s, 1);
                s += __shfl_xor(s, 2);
                s += __shfl_xor(s, 4);
                s += __shfl_xor(s, 8);
                float inv = 1.0f / s;
                int row = w * 16 + q * 4 + r;
                Ps[row * SP + 0 * 16 + nn] = (_Float16)(e0 * inv);
                Ps[row * SP + 1 * 16 + nn] = (_Float16)(e1 * inv);
                Ps[row * SP + 2 * 16 + nn] = (_Float16)(e2 * inv);
                Ps[row * SP + 3 * 16 + nn] = (_Float16)(e3 * inv);
            }
        }
        __syncthreads();   // P ready

        // ---- phase 6: new_e = P @ V, fused epilogue relu(r + new_e) (waves 4-7) ----
        if (w >= 4) {
            int j = w - 4;
            floatx4 pv[4][2];
            {
                floatx4 z = {0.f, 0.f, 0.f, 0.f};
                #pragma unroll
                for (int rt = 0; rt < 4; ++rt) { pv[rt][0] = z; pv[rt][1] = z; }
            }
            #pragma unroll
            for (int ks = 0; ks < 2; ++ks) {
                half8 ap[4];
                #pragma unroll
                for (int rt = 0; rt < 4; ++rt)
                    ap[rt] = *(const half8*)(Ps + (rt * 16 + nn) * SP + ks * 32 + q * 8);
                #pragma unroll
                for (int cl = 0; cl < 2; ++cl) {
                    half8 bv = *(const half8*)(Vt + ((2 * j + cl) * 16 + nn) * SVT + ks * 32 + q * 8);
                    #pragma unroll
                    for (int rt = 0; rt < 4; ++rt)
                        pv[rt][cl] = __builtin_amdgcn_mfma_f32_16x16x32_f16(ap[rt], bv, pv[rt][cl], 0, 0, 0);
                }
            }
            float* ob = outg + b * 8192;
            #pragma unroll
            for (int rt = 0; rt < 4; ++rt)
                #pragma unroll
                for (int cl = 0; cl < 2; ++cl) {
                    int colb = (2 * j + cl) * 16 + nn;   // matches R tile acc[rt][2+cl]
                    #pragma unroll
                    for (int r = 0; r < 4; ++r) {
                        int row = rt * 16 + q * 4 + r;
                        float v = acc[rt][2 + cl][r] + pv[rt][cl][r];
                        ob[row * 128 + colb] = fmaxf(v, 0.0f);
                    }
                }
        }
        __syncthreads();   // Vt consumed -> buffer free for next Xs

        // ---- write prefetched X(b+1) into LDS ----
        if (w < 4 && it + 1 < NB) {
            #pragma unroll
            for (int t = 0; t < 8; ++t) {
                int g = t * 256 + tid;
                int row = g >> 5, c4 = (g & 31) * 4;
                half4 h = { (_Float16)pf[t].x, (_Float16)pf[t].y,
                            (_Float16)pf[t].z, (_Float16)pf[t].w };
                *(half4*)(Xs + row * SX + c4) = h;
            }
        }
        __syncthreads();   // Xs(b+1) ready
    }
}

extern "C" void kernel_launch(void* const* d_in, const int* in_sizes, int n_in,
                              void* d_out, int out_size, void* d_ws, size_t ws_size,
                              hipStream_t stream) {
    const float* x  = (const float*)d_in[0];
    const float* Wq = (const float*)d_in[1];
    const float* Wk = (const float*)d_in[2];
    const float* Wv = (const float*)d_in[3];
    const float* Wr = (const float*)d_in[4];
    _Float16* Wh = (_Float16*)d_ws;      // 128x512 fp16 = 128 KB scratch
    float* out = (float*)d_out;

    wconv_kernel<<<256, 256, 0, stream>>>(Wq, Wk, Wv, Wr, Wh);
    autoint_kernel<<<1024, 512, 0, stream>>>(x, Wh, out);
}